// Round 5
// baseline (413.152 us; speedup 1.0000x reference)
//
#include <hip/hip_runtime.h>
#include <hip/hip_bf16.h>
#include <cstdint>

#define BATCH 32
#define CIN   256
#define COUT  256
#define HW    56
#define NEXP  8
#define HP    58

typedef __bf16 bf16x8 __attribute__((ext_vector_type(8)));
typedef float  f32x16 __attribute__((ext_vector_type(16)));
typedef unsigned short u16x8 __attribute__((ext_vector_type(8)));

static __device__ __forceinline__ unsigned short f32_to_bf16(float f) {
    uint32_t u = __builtin_bit_cast(uint32_t, f);
    return (unsigned short)((u + 0x7FFFu + ((u >> 16) & 1u)) >> 16);
}

// ---- zero the xtp halo (rows 0,57; cols 0,57) ----
__global__ void halo_kernel(unsigned short* __restrict__ xtp) {
    int b = blockIdx.x, t = threadIdx.x;
    unsigned short* base = xtp + (size_t)b * (HP * HP * CIN);
    // rows hp=0 and hp=57: 2 * 58*256 elems
    for (int j = t; j < 2 * HP * CIN; j += 256) {
        int row = (j < HP * CIN) ? 0 : 57;
        int k = j - (row ? HP * CIN : 0);
        base[((size_t)row * HP) * CIN + k] = 0;
    }
    // cols wp=0 and wp=57 for hp=1..56: 2 * 56*256
    for (int j = t; j < 2 * HW * CIN; j += 256) {
        int side = (j < HW * CIN) ? 0 : 1;
        int k = j - side * HW * CIN;
        int hp = 1 + (k >> 8), c = k & 255;
        base[((size_t)hp * HP + (side ? 57 : 0)) * CIN + c] = 0;
    }
}

// ---- x fp32 [b][c][56][56] -> xtp bf16 [b][58][58][c] + GAP sums ----
// one block per (h, b); thread = channel c; lane streams its own row.
__global__ void transpose_kernel(const float* __restrict__ x, unsigned short* __restrict__ xtp,
                                 float* __restrict__ gap) {
    int h = blockIdx.x, b = blockIdx.y, c = threadIdx.x;
    const float* src = x + ((size_t)(b * CIN + c) * HW + h) * HW;
    float4 v[14];
    float s = 0.f;
    #pragma unroll
    for (int j = 0; j < 14; ++j) {
        v[j] = reinterpret_cast<const float4*>(src)[j];
        s += v[j].x + v[j].y + v[j].z + v[j].w;
    }
    unsigned short* dst = xtp + ((size_t)(b * HP + h + 1) * HP + 1) * CIN + c;
    #pragma unroll
    for (int j = 0; j < 14; ++j) {
        dst[(j * 4 + 0) * CIN] = f32_to_bf16(v[j].x);
        dst[(j * 4 + 1) * CIN] = f32_to_bf16(v[j].y);
        dst[(j * 4 + 2) * CIN] = f32_to_bf16(v[j].z);
        dst[(j * 4 + 3) * CIN] = f32_to_bf16(v[j].w);
    }
    atomicAdd(&gap[b * CIN + c], s);
}

// ---- routing[b][e] = sigmoid(gapsum[b]·fc_w[e]/3136 + fc_b[e]) ----
__global__ void routing_kernel(const float* __restrict__ gap, const float* __restrict__ fcw,
                               const float* __restrict__ fcb, float* __restrict__ rout) {
    int t = threadIdx.x;
    int b = t >> 3, e = t & 7;
    const float* g = gap + b * CIN;
    const float* w = fcw + e * CIN;
    float z = 0.f;
    for (int c = 0; c < CIN; ++c) z += g[c] * w[c];
    z = z * (1.0f / 3136.0f) + fcb[e];
    rout[b * NEXP + e] = 1.f / (1.f + expf(-z));
}

// ---- cmb page layout: [b][ib][r] pages of 8192 elems = [khalf(2)][o(256)][lhi(2)][ch(8)] ----
__global__ void combine_kernel(const float* __restrict__ kw, const float* __restrict__ rout,
                               unsigned short* __restrict__ cmb) {
    int o = blockIdx.x;
    int t = threadIdx.x;             // channel i
    __shared__ float rs[BATCH][NEXP];
    rs[t >> 3][t & 7] = rout[t];
    __syncthreads();
    float kv[NEXP][9];
    #pragma unroll
    for (int e = 0; e < NEXP; ++e) {
        const float* p = kw + (((size_t)e * COUT + o) * CIN + t) * 9;
        #pragma unroll
        for (int r = 0; r < 9; ++r) kv[e][r] = p[r];
    }
    int ib = t >> 5, il = t & 31;
    int khalf = il >> 4, lhi = (il >> 3) & 1, ch = il & 7;
    int elem_in_page = khalf * 4096 + o * 16 + lhi * 8 + ch;
    for (int b = 0; b < BATCH; ++b) {
        size_t pbase = (size_t)(b * 72 + ib * 9) * 8192;
        #pragma unroll
        for (int r = 0; r < 9; ++r) {
            float s = 0.f;
            #pragma unroll
            for (int e = 0; e < NEXP; ++e) s += rs[b][e] * kv[e][r];
            cmb[pbase + (size_t)r * 8192 + elem_in_page] = f32_to_bf16(s);
        }
    }
}

// ---- conv: A global->reg (prefetch 1 step), B window in LDS (dbuf/ib), 8 barriers ----
// Block 256 thr = 4 waves; wave = 64o x 128px (acc[2][4]); tile 16h x 8w (ty=3: 8h, nf=2).
#define WBUF 12288

__global__ __launch_bounds__(256, 2)
void conv_kernel(const unsigned short* __restrict__ xtp, const unsigned short* __restrict__ cmb,
                 float* __restrict__ out) {
    __shared__ __align__(16) char lds[2 * WBUF];
    const int t = threadIdx.x, wave = t >> 6, l = t & 63;
    const int l31 = l & 31, lhi = l >> 5;

    // bijective XCD swizzle: 896 = 8 x 112
    int bid = blockIdx.x;
    int wg  = (bid & 7) * 112 + (bid >> 3);
    int b   = wg / 28, pt = wg - b * 28;
    int ty = pt / 7, tx = pt - ty * 7;
    const int nf  = (ty < 3) ? 4 : 2;
    const int chunks = (nf == 4) ? 720 : 400;   // (4*nf+2)*10*4
    int oh0 = ty * 16, ow0 = tx * 8;

    const unsigned short* xb = xtp + (size_t)b * (HP * HP * CIN);

    // per-lane window source offsets (chunk c = (wave+4k)*64 + l), source pre-swizzled
    int ws[3];
    #pragma unroll
    for (int k = 0; k < 3; ++k) {
        int c = (wave + 4 * k) * 64 + l;
        int cc = (c < chunks) ? c : 0;
        int pos = cc >> 2, q = (cc & 3) ^ ((pos >> 1) & 3);
        int hh = pos / 10, ww = pos - hh * 10;
        ws[k] = ((oh0 + hh) * HP + (ow0 + ww)) * CIN + q * 8;
    }

    // per-lane A base: page elem = khalf*4096 + o*16 + lhi*8 (+ch)
    const unsigned short* ap = cmb + (size_t)b * (72 * 8192) + (wave * 64 + l31) * 16 + lhi * 8;

    f32x16 acc[2][4];
    #pragma unroll
    for (int m = 0; m < 2; ++m)
        #pragma unroll
        for (int n = 0; n < 4; ++n)
            #pragma unroll
            for (int k = 0; k < 16; ++k) acc[m][n][k] = 0.f;

#define STAGE_W(ibx, buf)                                                                   \
    { _Pragma("unroll")                                                                     \
      for (int k = 0; k < 3; ++k) {                                                         \
        int g = wave + 4 * k;                                                               \
        if (g * 64 < chunks)                                                                \
            __builtin_amdgcn_global_load_lds(                                               \
                (const __attribute__((address_space(1))) void*)(xb + ws[k] + (ibx) * 32),   \
                (__attribute__((address_space(3))) void*)(lds + (buf) + g * 1024),          \
                16, 0, 0);                                                                  \
      } }

    // prologue: A(page 0) to regs + window ib=0
    u16x8 af[2][2];
    #pragma unroll
    for (int m = 0; m < 2; ++m)
        #pragma unroll
        for (int kh = 0; kh < 2; ++kh)
            af[m][kh] = *reinterpret_cast<const u16x8*>(ap + kh * 4096 + m * 512);
    STAGE_W(0, 0);
    __syncthreads();

    for (int ib = 0; ib < 8; ++ib) {
        if (ib < 7) STAGE_W(ib + 1, ((ib + 1) & 1) * WBUF);
        const char* curw = lds + (ib & 1) * WBUF;
        #pragma unroll
        for (int r = 0; r < 9; ++r) {
            const int s = ib * 9 + r;
            const int sn = (s < 71) ? s + 1 : 71;
            u16x8 afn[2][2];
            #pragma unroll
            for (int m = 0; m < 2; ++m)
                #pragma unroll
                for (int kh = 0; kh < 2; ++kh)
                    afn[m][kh] = *reinterpret_cast<const u16x8*>(
                        ap + (size_t)sn * 8192 + kh * 4096 + m * 512);
            const int dh = r / 3, dw = r - (r / 3) * 3;
            bf16x8 bfv[4][2];
            #pragma unroll
            for (int n = 0; n < 4; ++n) {
                if (n >= nf) continue;
                #pragma unroll
                for (int kh = 0; kh < 2; ++kh) {
                    int pos  = (n * 4 + (l31 >> 3) + dh) * 10 + (l31 & 7) + dw;
                    int slot = (kh * 2 + lhi) ^ ((pos >> 1) & 3);
                    bfv[n][kh] = *reinterpret_cast<const bf16x8*>(curw + (pos * 4 + slot) * 16);
                }
            }
            #pragma unroll
            for (int n = 0; n < 4; ++n) {
                if (n >= nf) continue;
                #pragma unroll
                for (int m = 0; m < 2; ++m)
                    #pragma unroll
                    for (int kh = 0; kh < 2; ++kh)
                        acc[m][n] = __builtin_amdgcn_mfma_f32_32x32x16_bf16(
                            __builtin_bit_cast(bf16x8, af[m][kh]), bfv[n][kh], acc[m][n], 0, 0, 0);
            }
            #pragma unroll
            for (int m = 0; m < 2; ++m)
                #pragma unroll
                for (int kh = 0; kh < 2; ++kh)
                    af[m][kh] = afn[m][kh];
        }
        __syncthreads();
    }

    // epilogue: D col = lane&31 (px), row = (reg&3)+8*(reg>>2)+4*lhi (o)
    #pragma unroll
    for (int m = 0; m < 2; ++m)
        #pragma unroll
        for (int n = 0; n < 4; ++n) {
            if (n >= nf) continue;
            int oh = oh0 + n * 4 + (l31 >> 3), ow = ow0 + (l31 & 7);
            #pragma unroll
            for (int reg = 0; reg < 16; ++reg) {
                int o = wave * 64 + m * 32 + (reg & 3) + 8 * (reg >> 2) + 4 * lhi;
                out[(((size_t)b * COUT + o) * HW + oh) * HW + ow] = acc[m][n][reg];
            }
        }
#undef STAGE_W
}

extern "C" void kernel_launch(void* const* d_in, const int* in_sizes, int n_in,
                              void* d_out, int out_size, void* d_ws, size_t ws_size,
                              hipStream_t stream) {
    const float* x   = (const float*)d_in[0];
    const float* kw  = (const float*)d_in[1];
    const float* fcw = (const float*)d_in[2];
    const float* fcb = (const float*)d_in[3];
    float* out = (float*)d_out;

    char* ws = (char*)d_ws;
    float* gap  = (float*)(ws + 0);                        //  32768 B
    float* rout = (float*)(ws + 32768);                    //   1024 B
    unsigned short* cmb = (unsigned short*)(ws + 33792);   // 37748736 B
    unsigned short* xtp = (unsigned short*)(ws + 33792 + 37748736); // 55107584 B

    hipMemsetAsync(gap, 0, BATCH * CIN * sizeof(float), stream);
    halo_kernel<<<dim3(BATCH), 256, 0, stream>>>(xtp);
    transpose_kernel<<<dim3(HW, BATCH), 256, 0, stream>>>(x, xtp, gap);
    routing_kernel<<<1, 256, 0, stream>>>(gap, fcw, fcb, rout);
    combine_kernel<<<COUT, 256, 0, stream>>>(kw, rout, cmb);
    conv_kernel<<<dim3(896), 256, 0, stream>>>(xtp, cmb, out);
}

// Round 6
// 361.029 us; speedup vs baseline: 1.1444x; 1.1444x over previous
//
#include <hip/hip_runtime.h>
#include <hip/hip_bf16.h>
#include <cstdint>

#define BATCH 32
#define CIN   256
#define COUT  256
#define HW    56
#define NEXP  8
#define HP    58

typedef __bf16 bf16x8 __attribute__((ext_vector_type(8)));
typedef float  f32x16 __attribute__((ext_vector_type(16)));
typedef unsigned short u16x8 __attribute__((ext_vector_type(8)));

static __device__ __forceinline__ unsigned short f32_to_bf16(float f) {
    uint32_t u = __builtin_bit_cast(uint32_t, f);
    return (unsigned short)((u + 0x7FFFu + ((u >> 16) & 1u)) >> 16);
}

// ---- x fp32 [b][i][56][56] -> xTp bf16 [b][58][58][i] (zero halo) + GAP row-sums ----
// (round-4 proven version: coalesced tile loads, halo written by wp/hp coverage)
__global__ void transpose_kernel(const float* __restrict__ x, unsigned short* __restrict__ xtp,
                                 float* __restrict__ gap) {
    int hp = blockIdx.x;
    int ib = blockIdx.y;
    int b  = blockIdx.z;
    int t  = threadIdx.x;
    __shared__ float tile[32][57];
    bool in_h = (hp >= 1 && hp <= HW);
    if (in_h) {
        const float* src = x + (((size_t)b * CIN + ib * 32) * HW + (hp - 1)) * HW;
        for (int idx = t; idx < 32 * HW; idx += 256) {
            int il = idx / HW, w = idx - il * HW;
            tile[il][w] = src[(size_t)il * (HW * HW) + w];
        }
    }
    __syncthreads();
    unsigned short* dst = xtp + (((size_t)b * HP + hp) * HP) * CIN + ib * 32;
    for (int idx = t; idx < HP * 32; idx += 256) {
        int wp = idx >> 5, il = idx & 31;
        float v = 0.f;
        if (in_h && wp >= 1 && wp <= HW) v = tile[il][wp - 1];
        dst[(size_t)wp * CIN + il] = f32_to_bf16(v);
    }
    if (in_h) {
        int c = t >> 3, j0 = t & 7;
        float s = 0.f;
        for (int j = j0; j < HW; j += 8) s += tile[c][j];
        s += __shfl_down(s, 4, 8);
        s += __shfl_down(s, 2, 8);
        s += __shfl_down(s, 1, 8);
        if (j0 == 0) atomicAdd(&gap[b * CIN + ib * 32 + c], s);
    }
}

// ---- routing[b][e] = sigmoid(gapsum[b]·fc_w[e]/3136 + fc_b[e]) ----
__global__ void routing_kernel(const float* __restrict__ gap, const float* __restrict__ fcw,
                               const float* __restrict__ fcb, float* __restrict__ rout) {
    int t = threadIdx.x;
    int b = t >> 3, e = t & 7;
    const float* g = gap + b * CIN;
    const float* w = fcw + e * CIN;
    float z = 0.f;
    for (int c = 0; c < CIN; ++c) z += g[c] * w[c];
    z = z * (1.0f / 3136.0f) + fcb[e];
    rout[b * NEXP + e] = 1.f / (1.f + expf(-z));
}

// ---- cmb page layout: [b][ib][r] pages of 8192 elems = [khalf(2)][o(256)][lhi(2)][ch(8)] ----
__global__ void combine_kernel(const float* __restrict__ kw, const float* __restrict__ rout,
                               unsigned short* __restrict__ cmb) {
    int o = blockIdx.x;
    int t = threadIdx.x;             // channel i
    __shared__ float rs[BATCH][NEXP];
    rs[t >> 3][t & 7] = rout[t];
    __syncthreads();
    float kv[NEXP][9];
    #pragma unroll
    for (int e = 0; e < NEXP; ++e) {
        const float* p = kw + (((size_t)e * COUT + o) * CIN + t) * 9;
        #pragma unroll
        for (int r = 0; r < 9; ++r) kv[e][r] = p[r];
    }
    int ib = t >> 5, il = t & 31;
    int khalf = il >> 4, lhi = (il >> 3) & 1, ch = il & 7;
    int elem_in_page = khalf * 4096 + o * 16 + lhi * 8 + ch;
    for (int b = 0; b < BATCH; ++b) {
        size_t pbase = (size_t)(b * 72 + ib * 9) * 8192;
        #pragma unroll
        for (int r = 0; r < 9; ++r) {
            float s = 0.f;
            #pragma unroll
            for (int e = 0; e < NEXP; ++e) s += rs[b][e] * kv[e][r];
            cmb[pbase + (size_t)r * 8192 + elem_in_page] = f32_to_bf16(s);
        }
    }
}

// ---- conv: 512 thr (8 waves = 4 o-quarters x 2 px-halves). Block 256o x 128px (16h x 8w).
// A: global->reg, 1-step prefetch (no LDS). B: window LDS dbuf per ib, XOR-slot swizzle.
// 8 barriers/block. Wave tile 64o x 64px, acc[2][2].
#define WBUF 12288

__global__ __launch_bounds__(512, 1)
void conv_kernel(const unsigned short* __restrict__ xtp, const unsigned short* __restrict__ cmb,
                 float* __restrict__ out) {
    __shared__ __align__(16) char lds[2 * WBUF];
    const int t = threadIdx.x, wave = t >> 6, l = t & 63;
    const int l31 = l & 31, lhi = l >> 5;
    const int wm = wave >> 1, wn = wave & 1;

    // bijective XCD swizzle: 896 = 8 x 112
    int bid = blockIdx.x;
    int wg  = (bid & 7) * 112 + (bid >> 3);
    int b   = wg / 28, pt = wg - b * 28;
    int ty = pt / 7, tx = pt - ty * 7;
    const bool shortT = (ty == 3);                 // only 8 output rows
    const int chunks = shortT ? 400 : 720;         // (rows+2)*10*4 16B-chunks per ib
    const bool active = !(shortT && wn == 1);
    int oh0 = ty * 16, ow0 = tx * 8;

    const unsigned short* xb = xtp + (size_t)b * (HP * HP * CIN);

    // per-lane window source offsets (chunk c = (wave + 8k)*64 + l), source pre-swizzled
    int ws[2];
    #pragma unroll
    for (int k = 0; k < 2; ++k) {
        int c = (wave + 8 * k) * 64 + l;
        int cc = (c < chunks) ? c : 0;
        int pos = cc >> 2, q = (cc & 3) ^ ((pos >> 1) & 3);
        int hh = pos / 10, ww = pos - hh * 10;
        ws[k] = ((oh0 + hh) * HP + (ow0 + ww)) * CIN + q * 8;
    }

    // per-lane A base: page elem = khalf*4096 + o*16 + lhi*8 (+ch); row = wm*64 + m*32 + l31
    const unsigned short* ap = cmb + (size_t)b * (72 * 8192) + (wm * 64 + l31) * 16 + lhi * 8;

#define STAGE_W(ibx, buf)                                                                   \
    { _Pragma("unroll")                                                                     \
      for (int k = 0; k < 2; ++k) {                                                         \
        int g = wave + 8 * k;                                                               \
        if (g * 64 < chunks)                                                                \
            __builtin_amdgcn_global_load_lds(                                               \
                (const __attribute__((address_space(1))) void*)(xb + ws[k] + (ibx) * 32),   \
                (__attribute__((address_space(3))) void*)(lds + (buf) + g * 1024),          \
                16, 0, 0);                                                                  \
      } }

    f32x16 acc[2][2];
    #pragma unroll
    for (int m = 0; m < 2; ++m)
        #pragma unroll
        for (int n = 0; n < 2; ++n)
            #pragma unroll
            for (int k = 0; k < 16; ++k) acc[m][n][k] = 0.f;

    // prologue: A(page 0) to regs + window ib=0
    u16x8 af[2][2];
    if (active) {
        #pragma unroll
        for (int m = 0; m < 2; ++m)
            #pragma unroll
            for (int kh = 0; kh < 2; ++kh)
                af[m][kh] = *reinterpret_cast<const u16x8*>(ap + kh * 4096 + m * 512);
    }
    STAGE_W(0, 0);
    __syncthreads();

    for (int ib = 0; ib < 8; ++ib) {
        if (ib < 7) STAGE_W(ib + 1, ((ib + 1) & 1) * WBUF);
        if (active) {
            const char* curw = lds + (ib & 1) * WBUF;
            #pragma unroll
            for (int r = 0; r < 9; ++r) {
                const int s = ib * 9 + r;
                const int sn = (s < 71) ? s + 1 : 71;
                u16x8 afn[2][2];
                #pragma unroll
                for (int m = 0; m < 2; ++m)
                    #pragma unroll
                    for (int kh = 0; kh < 2; ++kh)
                        afn[m][kh] = *reinterpret_cast<const u16x8*>(
                            ap + (size_t)sn * 8192 + kh * 4096 + m * 512);
                const int dh = r / 3, dw = r - (r / 3) * 3;
                bf16x8 bfv[2][2];
                #pragma unroll
                for (int n = 0; n < 2; ++n)
                    #pragma unroll
                    for (int kh = 0; kh < 2; ++kh) {
                        int pos  = (wn * 8 + n * 4 + (l31 >> 3) + dh) * 10 + (l31 & 7) + dw;
                        int slot = (kh * 2 + lhi) ^ ((pos >> 1) & 3);
                        bfv[n][kh] = *reinterpret_cast<const bf16x8*>(curw + (pos * 4 + slot) * 16);
                    }
                #pragma unroll
                for (int n = 0; n < 2; ++n)
                    #pragma unroll
                    for (int m = 0; m < 2; ++m)
                        #pragma unroll
                        for (int kh = 0; kh < 2; ++kh)
                            acc[m][n] = __builtin_amdgcn_mfma_f32_32x32x16_bf16(
                                __builtin_bit_cast(bf16x8, af[m][kh]), bfv[n][kh], acc[m][n], 0, 0, 0);
                #pragma unroll
                for (int m = 0; m < 2; ++m)
                    #pragma unroll
                    for (int kh = 0; kh < 2; ++kh)
                        af[m][kh] = afn[m][kh];
            }
        }
        __syncthreads();
    }

    if (active) {
        // epilogue: D col = lane&31 (px), row = (reg&3)+8*(reg>>2)+4*lhi (o)
        #pragma unroll
        for (int m = 0; m < 2; ++m)
            #pragma unroll
            for (int n = 0; n < 2; ++n) {
                int oh = oh0 + wn * 8 + n * 4 + (l31 >> 3), ow = ow0 + (l31 & 7);
                #pragma unroll
                for (int reg = 0; reg < 16; ++reg) {
                    int o = wm * 64 + m * 32 + (reg & 3) + 8 * (reg >> 2) + 4 * lhi;
                    out[(((size_t)b * COUT + o) * HW + oh) * HW + ow] = acc[m][n][reg];
                }
            }
    }
#undef STAGE_W
}

extern "C" void kernel_launch(void* const* d_in, const int* in_sizes, int n_in,
                              void* d_out, int out_size, void* d_ws, size_t ws_size,
                              hipStream_t stream) {
    const float* x   = (const float*)d_in[0];
    const float* kw  = (const float*)d_in[1];
    const float* fcw = (const float*)d_in[2];
    const float* fcb = (const float*)d_in[3];
    float* out = (float*)d_out;

    char* ws = (char*)d_ws;
    float* gap  = (float*)(ws + 0);                        //  32768 B
    float* rout = (float*)(ws + 32768);                    //   1024 B
    unsigned short* cmb = (unsigned short*)(ws + 33792);   // 37748736 B
    unsigned short* xtp = (unsigned short*)(ws + 33792 + 37748736); // 55107584 B

    hipMemsetAsync(gap, 0, BATCH * CIN * sizeof(float), stream);
    transpose_kernel<<<dim3(HP, 8, BATCH), 256, 0, stream>>>(x, xtp, gap);
    routing_kernel<<<1, 256, 0, stream>>>(gap, fcw, fcb, rout);
    combine_kernel<<<COUT, 256, 0, stream>>>(kw, rout, cmb);
    conv_kernel<<<dim3(896), 512, 0, stream>>>(xtp, cmb, out);
}

// Round 7
// 251.282 us; speedup vs baseline: 1.6442x; 1.4367x over previous
//
#include <hip/hip_runtime.h>
#include <hip/hip_bf16.h>
#include <cstdint>

#define BATCH 32
#define CIN   256
#define COUT  256
#define HW    56
#define NEXP  8
#define HP    58

typedef __bf16 bf16x8 __attribute__((ext_vector_type(8)));
typedef float  f32x16 __attribute__((ext_vector_type(16)));
typedef unsigned short u16x8 __attribute__((ext_vector_type(8)));

static __device__ __forceinline__ unsigned short f32_to_bf16(float f) {
    uint32_t u = __builtin_bit_cast(uint32_t, f);
    return (unsigned short)((u + 0x7FFFu + ((u >> 16) & 1u)) >> 16);
}

// ---- x fp32 [b][i][56][56] -> xTp bf16 [b][58][58][i] (zero halo) + GAP row-sums ----
__global__ void transpose_kernel(const float* __restrict__ x, unsigned short* __restrict__ xtp,
                                 float* __restrict__ gap) {
    int hp = blockIdx.x;
    int ib = blockIdx.y;
    int b  = blockIdx.z;
    int t  = threadIdx.x;
    __shared__ float tile[32][57];
    bool in_h = (hp >= 1 && hp <= HW);
    if (in_h) {
        const float* src = x + (((size_t)b * CIN + ib * 32) * HW + (hp - 1)) * HW;
        for (int idx = t; idx < 32 * HW; idx += 256) {
            int il = idx / HW, w = idx - il * HW;
            tile[il][w] = src[(size_t)il * (HW * HW) + w];
        }
    }
    __syncthreads();
    unsigned short* dst = xtp + (((size_t)b * HP + hp) * HP) * CIN + ib * 32;
    for (int idx = t; idx < HP * 32; idx += 256) {
        int wp = idx >> 5, il = idx & 31;
        float v = 0.f;
        if (in_h && wp >= 1 && wp <= HW) v = tile[il][wp - 1];
        dst[(size_t)wp * CIN + il] = f32_to_bf16(v);
    }
    if (in_h) {
        int c = t >> 3, j0 = t & 7;
        float s = 0.f;
        for (int j = j0; j < HW; j += 8) s += tile[c][j];
        s += __shfl_down(s, 4, 8);
        s += __shfl_down(s, 2, 8);
        s += __shfl_down(s, 1, 8);
        if (j0 == 0) atomicAdd(&gap[b * CIN + ib * 32 + c], s);
    }
}

// ---- routing[b][e] = sigmoid(gapsum[b]·fc_w[e]/3136 + fc_b[e]) ----
__global__ void routing_kernel(const float* __restrict__ gap, const float* __restrict__ fcw,
                               const float* __restrict__ fcb, float* __restrict__ rout) {
    int t = threadIdx.x;
    int b = t >> 3, e = t & 7;
    const float* g = gap + b * CIN;
    const float* w = fcw + e * CIN;
    float z = 0.f;
    for (int c = 0; c < CIN; ++c) z += g[c] * w[c];
    z = z * (1.0f / 3136.0f) + fcb[e];
    rout[b * NEXP + e] = 1.f / (1.f + expf(-z));
}

// ---- cmb page layout: [b][ib][r] pages of 8192 elems = [khalf(2)][o(256)][lhi(2)][ch(8)] ----
// LDS-staged version with 16B vector stores; grid (COUT, 4) with 8 batches per block.
__global__ void combine_kernel(const float* __restrict__ kw, const float* __restrict__ rout,
                               unsigned short* __restrict__ cmb) {
    int o  = blockIdx.x;
    int bq = blockIdx.y;             // batch quarter
    int t  = threadIdx.x;            // channel i
    __shared__ float rs[BATCH][NEXP];
    __shared__ __align__(16) unsigned short sbuf[8][9][32];
    rs[t >> 3][t & 7] = rout[t];
    __syncthreads();
    float kv[NEXP][9];
    #pragma unroll
    for (int e = 0; e < NEXP; ++e) {
        const float* p = kw + (((size_t)e * COUT + o) * CIN + t) * 9;
        #pragma unroll
        for (int r = 0; r < 9; ++r) kv[e][r] = p[r];
    }
    int ib = t >> 5, il = t & 31;
    for (int bb = 0; bb < 8; ++bb) {
        int b = bq * 8 + bb;
        #pragma unroll
        for (int r = 0; r < 9; ++r) {
            float s = 0.f;
            #pragma unroll
            for (int e = 0; e < NEXP; ++e) s += rs[b][e] * kv[e][r];
            sbuf[ib][r][il] = f32_to_bf16(s);
        }
        __syncthreads();
        // 288 vector stores of 16B: sid -> (ib2, r, khalf, lhi)
        for (int sid = t; sid < 288; sid += 256) {
            int ib2 = sid / 36, rem = sid % 36;
            int rr = rem >> 2, kq = rem & 3;
            int khalf = kq >> 1, lhi = kq & 1;
            size_t dst = (size_t)(b * 72 + ib2 * 9 + rr) * 8192 + khalf * 4096 + o * 16 + lhi * 8;
            *reinterpret_cast<u16x8*>(cmb + dst) =
                *reinterpret_cast<const u16x8*>(&sbuf[ib2][rr][khalf * 16 + lhi * 8]);
        }
        __syncthreads();
    }
}

// ---- conv: 256 thr (4 waves = 2 o-halves x 2 px-halves). Grid (896, 2).
// Block tile: 128o x 128px (16h x 8w). Wave: 64o x 64px, acc[2][2], 32x32x16 MFMA.
// A: global->reg, 1-step prefetch. B: window LDS dbuf per ib, 80B-padded rows
// (conflict-free: pos stride 20 dwords covers all 32 banks in any 8-lane group).
#define WBUF 15360

__global__ __launch_bounds__(256, 3)
void conv_kernel(const unsigned short* __restrict__ xtp, const unsigned short* __restrict__ cmb,
                 float* __restrict__ out) {
    __shared__ __align__(16) char lds[2 * WBUF];
    const int t = threadIdx.x, wave = t >> 6, l = t & 63;
    const int l31 = l & 31, lhi = l >> 5;
    const int wm = wave >> 1, wn = wave & 1;

    // bijective XCD swizzle on x: 896 = 8 x 112
    int bid = blockIdx.x;
    int wg  = (bid & 7) * 112 + (bid >> 3);
    int b   = wg / 28, pt = wg - b * 28;
    int ty = pt / 7, tx = pt - ty * 7;
    const bool shortT = (ty == 3);                 // only 8 output rows
    const int chunks = shortT ? 500 : 900;         // pos*5 16B-slots per ib (slot 4 = pad)
    const bool active = !(shortT && wn == 1);
    int oh0 = ty * 16, ow0 = tx * 8;
    int o0  = blockIdx.y * 128;

    const unsigned short* xb = xtp + (size_t)b * (HP * HP * CIN);

    // per-lane window source offsets; chunk c -> pos = c/5, q = c%5 (q==4: pad, dup q0)
    int ws[4];
    #pragma unroll
    for (int k = 0; k < 4; ++k) {
        int c = (wave + 4 * k) * 64 + l;
        int cc = (c < chunks) ? c : 0;
        int pos = cc / 5, q = cc - pos * 5;
        if (q == 4) q = 0;
        int hh = pos / 10, ww = pos - hh * 10;
        ws[k] = ((oh0 + hh) * HP + (ow0 + ww)) * CIN + q * 8;
    }

    // per-lane A base: page elem = khalf*4096 + o*16 + lhi*8; row = o0 + wm*64 + m*32 + l31
    const unsigned short* ap = cmb + (size_t)b * (72 * 8192) + (o0 + wm * 64 + l31) * 16 + lhi * 8;

#define STAGE_W(ibx, buf)                                                                   \
    { _Pragma("unroll")                                                                     \
      for (int k = 0; k < 4; ++k) {                                                         \
        int g = wave + 4 * k;                                                               \
        if (g * 64 < chunks)                                                                \
            __builtin_amdgcn_global_load_lds(                                               \
                (const __attribute__((address_space(1))) void*)(xb + ws[k] + (ibx) * 32),   \
                (__attribute__((address_space(3))) void*)(lds + (buf) + g * 1024),          \
                16, 0, 0);                                                                  \
      } }

    f32x16 acc[2][2];
    #pragma unroll
    for (int m = 0; m < 2; ++m)
        #pragma unroll
        for (int n = 0; n < 2; ++n)
            #pragma unroll
            for (int k = 0; k < 16; ++k) acc[m][n][k] = 0.f;

    // prologue: A(page 0) to regs + window ib=0
    u16x8 af[2][2];
    if (active) {
        #pragma unroll
        for (int m = 0; m < 2; ++m)
            #pragma unroll
            for (int kh = 0; kh < 2; ++kh)
                af[m][kh] = *reinterpret_cast<const u16x8*>(ap + kh * 4096 + m * 512);
    }
    STAGE_W(0, 0);
    __syncthreads();

    for (int ib = 0; ib < 8; ++ib) {
        if (ib < 7) STAGE_W(ib + 1, ((ib + 1) & 1) * WBUF);
        if (active) {
            const char* curw = lds + (ib & 1) * WBUF;
            #pragma unroll
            for (int r = 0; r < 9; ++r) {
                const int s = ib * 9 + r;
                const int sn = (s < 71) ? s + 1 : 71;
                u16x8 afn[2][2];
                #pragma unroll
                for (int m = 0; m < 2; ++m)
                    #pragma unroll
                    for (int kh = 0; kh < 2; ++kh)
                        afn[m][kh] = *reinterpret_cast<const u16x8*>(
                            ap + (size_t)sn * 8192 + kh * 4096 + m * 512);
                const int dh = r / 3, dw = r - (r / 3) * 3;
                bf16x8 bfv[2][2];
                #pragma unroll
                for (int n = 0; n < 2; ++n)
                    #pragma unroll
                    for (int kh = 0; kh < 2; ++kh) {
                        int pos = (wn * 8 + n * 4 + (l31 >> 3) + dh) * 10 + (l31 & 7) + dw;
                        bfv[n][kh] = *reinterpret_cast<const bf16x8*>(
                            curw + pos * 80 + (kh * 2 + lhi) * 16);
                    }
                #pragma unroll
                for (int n = 0; n < 2; ++n)
                    #pragma unroll
                    for (int m = 0; m < 2; ++m)
                        #pragma unroll
                        for (int kh = 0; kh < 2; ++kh)
                            acc[m][n] = __builtin_amdgcn_mfma_f32_32x32x16_bf16(
                                __builtin_bit_cast(bf16x8, af[m][kh]), bfv[n][kh], acc[m][n], 0, 0, 0);
                #pragma unroll
                for (int m = 0; m < 2; ++m)
                    #pragma unroll
                    for (int kh = 0; kh < 2; ++kh)
                        af[m][kh] = afn[m][kh];
            }
        }
        __syncthreads();
    }

    if (active) {
        // epilogue: D col = lane&31 (px), row = (reg&3)+8*(reg>>2)+4*lhi (o)
        #pragma unroll
        for (int m = 0; m < 2; ++m)
            #pragma unroll
            for (int n = 0; n < 2; ++n) {
                int oh = oh0 + wn * 8 + n * 4 + (l31 >> 3), ow = ow0 + (l31 & 7);
                #pragma unroll
                for (int reg = 0; reg < 16; ++reg) {
                    int o = o0 + wm * 64 + m * 32 + (reg & 3) + 8 * (reg >> 2) + 4 * lhi;
                    out[(((size_t)b * COUT + o) * HW + oh) * HW + ow] = acc[m][n][reg];
                }
            }
    }
#undef STAGE_W
}

extern "C" void kernel_launch(void* const* d_in, const int* in_sizes, int n_in,
                              void* d_out, int out_size, void* d_ws, size_t ws_size,
                              hipStream_t stream) {
    const float* x   = (const float*)d_in[0];
    const float* kw  = (const float*)d_in[1];
    const float* fcw = (const float*)d_in[2];
    const float* fcb = (const float*)d_in[3];
    float* out = (float*)d_out;

    char* ws = (char*)d_ws;
    float* gap  = (float*)(ws + 0);                        //  32768 B
    float* rout = (float*)(ws + 32768);                    //   1024 B
    unsigned short* cmb = (unsigned short*)(ws + 33792);   // 37748736 B
    unsigned short* xtp = (unsigned short*)(ws + 33792 + 37748736); // 55107584 B

    hipMemsetAsync(gap, 0, BATCH * CIN * sizeof(float), stream);
    transpose_kernel<<<dim3(HP, 8, BATCH), 256, 0, stream>>>(x, xtp, gap);
    routing_kernel<<<1, 256, 0, stream>>>(gap, fcw, fcb, rout);
    combine_kernel<<<dim3(COUT, 4), 256, 0, stream>>>(kw, rout, cmb);
    conv_kernel<<<dim3(896, 2), 256, 0, stream>>>(xtp, cmb, out);
}